// Round 3
// baseline (2292.341 us; speedup 1.0000x reference)
//
#include <hip/hip_runtime.h>
#include <hip/hip_bf16.h>

#define T_LEN 4096

typedef __attribute__((ext_vector_type(8))) short bfrag8;
typedef __attribute__((ext_vector_type(4))) float f32x4;

// Workgroup barrier WITHOUT vmcnt(0) drain: keeps global prefetch loads in
// flight across the barrier (the __syncthreads() lowering would drain them).
__device__ __forceinline__ void wg_barrier() {
  asm volatile("s_waitcnt lgkmcnt(0)\ns_barrier" ::: "memory");
}

__device__ __forceinline__ float fact(float x, float S, float A, float B) {
  // sigmoid: S=-1/ln2, A=0, B=1 ;  tanh: S=+2/ln2, A=1, B=-2
  float e = __builtin_amdgcn_exp2f(S * x);
  return A + B * __builtin_amdgcn_rcpf(1.0f + e);
}
__device__ __forceinline__ float ftanh(float x) {
  float e = __builtin_amdgcn_exp2f(2.8853900817779268f * x);
  return 1.0f - 2.0f * __builtin_amdgcn_rcpf(1.0f + e);
}
// Broadcast lane SEL within each aligned 4-lane group (quad_perm DPP, VALU).
template <int SEL>
__device__ __forceinline__ float qb(float v) {
  union { float f; int i; } u;
  u.f = v;
  u.i = __builtin_amdgcn_mov_dpp(u.i, SEL * 0x55, 0xF, 0xF, true);
  return u.f;
}

// ---------------------------------------------------------------------------
// Kernel 1: fused+permuted weights, K=128.
//   cols [0,60)  = sum_e W_ih[no][e] * W_enc[e][k]   (encoder folded in)
//   cols [60,64) = 0 (pad)
//   cols [64,128)= W_hh[no][k-64]
// Permuted row np (w=np>>5, half=(np>>4)&1, l15=np&15):
//   unit = 8w + 4*half + (l15>>2), gate = l15&3, no = gate*64 + unit.
// biasc[dir][np] = b[no] + W_ih[no]·b_enc  (fp32).
// ---------------------------------------------------------------------------
__global__ void prep_weights(const float* __restrict__ W_enc,
                             const float* __restrict__ b_enc,
                             const float* __restrict__ W_ih_f,
                             const float* __restrict__ W_hh_f,
                             const float* __restrict__ b_f,
                             const float* __restrict__ W_ih_b,
                             const float* __restrict__ W_hh_b,
                             const float* __restrict__ b_b,
                             __hip_bfloat16* __restrict__ Wc,
                             float* __restrict__ biasc) {
  const int dir = blockIdx.x;
  const int np = threadIdx.x;
  const int w = np >> 5, half = (np >> 4) & 1, l15 = np & 15;
  const int unit = 8 * w + 4 * half + (l15 >> 2);
  const int gate = l15 & 3;
  const int no = gate * 64 + unit;
  const float* W_ih = dir ? W_ih_b : W_ih_f;
  const float* W_hh = dir ? W_hh_b : W_hh_f;
  const float* bv = dir ? b_b : b_f;

  float wi[32];
#pragma unroll
  for (int e = 0; e < 32; ++e) wi[e] = W_ih[no * 32 + e];

  __hip_bfloat16* row = Wc + (size_t)(dir * 256 + np) * 128;
  for (int k = 0; k < 60; ++k) {
    float v = 0.0f;
#pragma unroll
    for (int e = 0; e < 32; ++e) v += wi[e] * W_enc[e * 60 + k];
    row[k] = __float2bfloat16(v);
  }
#pragma unroll
  for (int k = 60; k < 64; ++k) row[k] = __float2bfloat16(0.0f);
#pragma unroll
  for (int j = 0; j < 64; ++j) row[64 + j] = __float2bfloat16(W_hh[no * 64 + j]);

  float bb = bv[no];
#pragma unroll
  for (int e = 0; e < 32; ++e) bb += wi[e] * b_enc[e];
  biasc[dir * 256 + np] = bb;
}

// ---------------------------------------------------------------------------
// Kernel 2: the recurrence. 256 WGs = 128 batch-pairs x 2 dirs, 512 thr
// (8 waves, 2/SIMD, 1 WG/CU -> ALL 256 CUs busy).
// Per wave: 2 N-tiles (32 permuted gate cols), K=128:
//   K [0,64)  = c-feats (fp32 global prefetch depth 4, cvt to bf16 at use)
//   K [64,128)= h from LDS ping-pong (2 x ds_read_b128)
// acc_x (2-chain, reg inputs, starts at barrier) || acc_h (2-chain after ds),
// summed per-lane: each lane owns ONE gate value (batch=quad&1, tile=quad>>1,
// col=l15) -> 1 fact/lane; 4-lane group = 4 gates of one unit -> DPP gather;
// redundant per-group cell update; 1 lgkm-only barrier per step.
// ---------------------------------------------------------------------------
__global__ __launch_bounds__(512) void lstm_main(
    const float* __restrict__ cin, const __hip_bfloat16* __restrict__ Wc,
    const float* __restrict__ biasc, float* __restrict__ cfin) {
  __shared__ short Hbuf[2][160];  // [buf][(batch)*80 + unit], stride 80 pads banks

  const int tid = threadIdx.x, lane = tid & 63, wave = tid >> 6;
  const int quad = lane >> 4, l15 = lane & 15;
  const int g = lane & 3;
  const int batch = quad & 1;    // my gate value's batch row
  const int tile = quad >> 1;    // my gate value's N-tile (0: cols l15, 1: +16)
  const int unit = 8 * wave + 4 * tile + (l15 >> 2);
  const int dir = (int)blockIdx.x >> 7;
  const int b0 = ((int)blockIdx.x & 127) << 1;

  // loop-invariant weight fragments (B-operand: lane = col n, k = quad*8+j)
  const int n0 = wave * 32 + l15;
  const __hip_bfloat16* wr0 = Wc + (size_t)(dir * 256 + n0) * 128 + quad * 8;
  const __hip_bfloat16* wr1 = wr0 + (size_t)16 * 128;
  bfrag8 wf0[4], wf1[4];
#pragma unroll
  for (int kt = 0; kt < 4; ++kt) {
    wf0[kt] = *(const bfrag8*)(wr0 + kt * 32);
    wf1[kt] = *(const bfrag8*)(wr1 + kt * 32);
  }
  const float bias0 = biasc[dir * 256 + n0];
  const float bias1 = biasc[dir * 256 + n0 + 16];

  // activation constants for my gate column (g==2 is the tanh gate)
  const bool isg = (g == 2);
  const float S = isg ? 2.8853900817779268f : -1.4426950408889634f;
  const float Aa = isg ? 1.0f : 0.0f;
  const float Bb = isg ? -2.0f : 1.0f;

  // A-operand row m holds batch m&1 -> this lane loads/reads batch lane&1
  const float* crow = cin + (size_t)(b0 + (lane & 1)) * T_LEN * 60;
  const int o0a = quad * 8;                          // cols  q*8 .. q*8+3
  const int o0b = o0a + 4;                           // cols  q*8+4 .. q*8+7
  const int o1a = 32 + quad * 8;                     // cols 32+q*8 ..
  const int o1b = (quad == 3) ? 56 : (36 + quad * 8); // q3: dup 56-59, zeroed

  if (tid < 320) ((short*)Hbuf)[tid] = 0;  // h0 = 0 (both buffers)

  float4 p0a[4], p0b[4], p1a[4], p1b[4];   // depth-4 prefetch of c-row chunks
#pragma unroll
  for (int q = 0; q < 4; ++q) {
    int tp = dir ? (T_LEN - 1 - q) : q;
    const float* base = crow + (size_t)tp * 60;
    p0a[q] = *(const float4*)(base + o0a);
    p0b[q] = *(const float4*)(base + o0b);
    p1a[q] = *(const float4*)(base + o1a);
    p1b[q] = *(const float4*)(base + o1b);
  }

  float cst = 0.f;
  const int hr = (lane & 1) * 80 + quad * 8;  // A-frag h read base (shorts)
  const int hw = batch * 80 + unit;           // h write slot
  wg_barrier();

#pragma unroll 4
  for (int t = 0; t < T_LEN; ++t) {
    const int cur = t & 1;
    // ---- build c-feat A-frags (K 0..64) from prefetched registers ----
    float4 va = p0a[t & 3], vb = p0b[t & 3], vc = p1a[t & 3], vd = p1b[t & 3];
    if (quad == 3) { vd.x = 0.f; vd.y = 0.f; vd.z = 0.f; vd.w = 0.f; }  // K pad 60-63
    union { bfrag8 v; __hip_bfloat16 h[8]; } A0, A1;
    A0.h[0] = __float2bfloat16(va.x); A0.h[1] = __float2bfloat16(va.y);
    A0.h[2] = __float2bfloat16(va.z); A0.h[3] = __float2bfloat16(va.w);
    A0.h[4] = __float2bfloat16(vb.x); A0.h[5] = __float2bfloat16(vb.y);
    A0.h[6] = __float2bfloat16(vb.z); A0.h[7] = __float2bfloat16(vb.w);
    A1.h[0] = __float2bfloat16(vc.x); A1.h[1] = __float2bfloat16(vc.y);
    A1.h[2] = __float2bfloat16(vc.z); A1.h[3] = __float2bfloat16(vc.w);
    A1.h[4] = __float2bfloat16(vd.x); A1.h[5] = __float2bfloat16(vd.y);
    A1.h[6] = __float2bfloat16(vd.z); A1.h[7] = __float2bfloat16(vd.w);
    // ---- h A-frags from LDS (issued early; latency overlaps x-MFMAs) ----
    bfrag8 ahA = *(const bfrag8*)&Hbuf[cur][hr];
    bfrag8 ahB = *(const bfrag8*)&Hbuf[cur][hr + 32];
    // ---- prefetch c chunks for t+4 (in flight across the lgkm barrier) ----
    {
      int tn = t + 4; if (tn > T_LEN - 1) tn = T_LEN - 1;
      int tp = dir ? (T_LEN - 1 - tn) : tn;
      const float* base = crow + (size_t)tp * 60;
      p0a[t & 3] = *(const float4*)(base + o0a);
      p0b[t & 3] = *(const float4*)(base + o0b);
      p1a[t & 3] = *(const float4*)(base + o1a);
      p1b[t & 3] = *(const float4*)(base + o1b);
    }
    // ---- MFMAs: two independent 2-chains per N-tile ----
    f32x4 accx0 = {bias0, bias0, bias0, bias0};
    f32x4 accx1 = {bias1, bias1, bias1, bias1};
    accx0 = __builtin_amdgcn_mfma_f32_16x16x32_bf16(A0.v, wf0[0], accx0, 0, 0, 0);
    accx1 = __builtin_amdgcn_mfma_f32_16x16x32_bf16(A0.v, wf1[0], accx1, 0, 0, 0);
    accx0 = __builtin_amdgcn_mfma_f32_16x16x32_bf16(A1.v, wf0[1], accx0, 0, 0, 0);
    accx1 = __builtin_amdgcn_mfma_f32_16x16x32_bf16(A1.v, wf1[1], accx1, 0, 0, 0);
    f32x4 acch0 = {0.f, 0.f, 0.f, 0.f};
    f32x4 acch1 = {0.f, 0.f, 0.f, 0.f};
    acch0 = __builtin_amdgcn_mfma_f32_16x16x32_bf16(ahA, wf0[2], acch0, 0, 0, 0);
    acch1 = __builtin_amdgcn_mfma_f32_16x16x32_bf16(ahA, wf1[2], acch1, 0, 0, 0);
    acch0 = __builtin_amdgcn_mfma_f32_16x16x32_bf16(ahB, wf0[3], acch0, 0, 0, 0);
    acch1 = __builtin_amdgcn_mfma_f32_16x16x32_bf16(ahB, wf1[3], acch1, 0, 0, 0);
    // ---- my single gate value: D row r = batch r&1 -> reg index = batch ----
    float vx = tile ? (batch ? accx1[1] : accx1[0]) : (batch ? accx0[1] : accx0[0]);
    float vh = tile ? (batch ? acch1[1] : acch1[0]) : (batch ? acch0[1] : acch0[0]);
    float a = fact(vx + vh, S, Aa, Bb);
    // gather the 4 gates of my unit from my aligned 4-lane group (i,f,g,o)
    float gi = qb<0>(a), gf = qb<1>(a), gg = qb<2>(a), go = qb<3>(a);
    cst = gf * cst + gi * gg;
    float h = go * ftanh(cst);
    if (g == 0) *(__hip_bfloat16*)&Hbuf[cur ^ 1][hw] = __float2bfloat16(h);
    wg_barrier();
  }

  if (g == 0) {  // reference quirk: final CELL state feeds the FC
    cfin[(size_t)(dir * 256 + b0 + batch) * 64 + unit] = cst;
  }
}

// ---------------------------------------------------------------------------
// Kernel 3: out[b,:] = [c_fwd(b) ; c_bwd(b)] @ W_fin^T + b_fin
// ---------------------------------------------------------------------------
__global__ void final_fc(const float* __restrict__ cfin,
                         const float* __restrict__ W_fin,
                         const float* __restrict__ b_fin,
                         float* __restrict__ out) {
  int b = threadIdx.x;  // 256 threads, 1 block
  const float* cf = cfin + (size_t)b * 64;
  const float* cb = cfin + (size_t)(256 + b) * 64;
  float a0 = b_fin[0], a1 = b_fin[1], a2 = b_fin[2];
  for (int u = 0; u < 64; ++u) {
    float vf = cf[u], vb = cb[u];
    a0 += W_fin[0 * 128 + u] * vf + W_fin[0 * 128 + 64 + u] * vb;
    a1 += W_fin[1 * 128 + u] * vf + W_fin[1 * 128 + 64 + u] * vb;
    a2 += W_fin[2 * 128 + u] * vf + W_fin[2 * 128 + 64 + u] * vb;
  }
  out[b * 3 + 0] = a0;
  out[b * 3 + 1] = a1;
  out[b * 3 + 2] = a2;
}

extern "C" void kernel_launch(void* const* d_in, const int* in_sizes, int n_in,
                              void* d_out, int out_size, void* d_ws, size_t ws_size,
                              hipStream_t stream) {
  (void)in_sizes; (void)n_in; (void)out_size; (void)ws_size;
  const float* c      = (const float*)d_in[0];
  const float* W_enc  = (const float*)d_in[1];
  const float* b_enc  = (const float*)d_in[2];
  const float* W_ih_f = (const float*)d_in[3];
  const float* W_hh_f = (const float*)d_in[4];
  const float* b_f    = (const float*)d_in[5];
  const float* W_ih_b = (const float*)d_in[6];
  const float* W_hh_b = (const float*)d_in[7];
  const float* b_b    = (const float*)d_in[8];
  const float* W_fin  = (const float*)d_in[9];
  const float* b_fin  = (const float*)d_in[10];
  float* out = (float*)d_out;

  char* ws = (char*)d_ws;
  __hip_bfloat16* Wc = (__hip_bfloat16*)ws;           // 2*256*128*2 = 131072 B
  float* biasc = (float*)(ws + 131072);               // 2*256*4    = 2048 B
  float* cfin  = (float*)(ws + 131072 + 2048);        // 2*256*64*4 = 131072 B

  prep_weights<<<2, 256, 0, stream>>>(W_enc, b_enc, W_ih_f, W_hh_f, b_f,
                                      W_ih_b, W_hh_b, b_b, Wc, biasc);
  lstm_main<<<256, 512, 0, stream>>>(c, Wc, biasc, cfin);
  final_fc<<<1, 256, 0, stream>>>(cfin, W_fin, b_fin, out);
}

// Round 4
// 1574.145 us; speedup vs baseline: 1.4562x; 1.4562x over previous
//
#include <hip/hip_runtime.h>
#include <hip/hip_bf16.h>

#define T_LEN 4096

typedef __attribute__((ext_vector_type(8))) short bfrag8;
typedef __attribute__((ext_vector_type(4))) float f32x4;

// Workgroup barrier WITHOUT vmcnt(0) drain: keeps global prefetch loads in
// flight across the barrier (the __syncthreads() lowering would drain them).
__device__ __forceinline__ void wg_barrier() {
  asm volatile("s_waitcnt lgkmcnt(0)\ns_barrier" ::: "memory");
}

__device__ __forceinline__ float fact(float x, float S, float A, float B) {
  // sigmoid: S=-1/ln2, A=0, B=1 ;  tanh: S=+2/ln2, A=1, B=-2
  float e = __builtin_amdgcn_exp2f(S * x);
  return A + B * __builtin_amdgcn_rcpf(1.0f + e);
}
__device__ __forceinline__ float ftanh(float x) {
  float e = __builtin_amdgcn_exp2f(2.8853900817779268f * x);
  return 1.0f - 2.0f * __builtin_amdgcn_rcpf(1.0f + e);
}
// Broadcast lane SEL within each aligned 4-lane group (quad_perm DPP, VALU).
template <int SEL>
__device__ __forceinline__ float qb(float v) {
  union { float f; int i; } u;
  u.f = v;
  u.i = __builtin_amdgcn_mov_dpp(u.i, SEL * 0x55, 0xF, 0xF, true);
  return u.f;
}

// ---------------------------------------------------------------------------
// Kernel 0: bf16 copy of W_enc padded to K=64 (B-operand for the encoder).
// ---------------------------------------------------------------------------
__global__ void prep_enc(const float* __restrict__ W_enc,
                         __hip_bfloat16* __restrict__ Wencb) {
  int u = threadIdx.x;
  if (u < 32) {
    for (int k = 0; k < 64; ++k)
      Wencb[u * 64 + k] = __float2bfloat16(k < 60 ? W_enc[u * 60 + k] : 0.0f);
  }
}

// ---------------------------------------------------------------------------
// Kernel 1: MFMA encoder  x[row][u] = sum_k c[row][k] * W_enc[u][k]  (bf16).
// One wave per 16 rows: A = c (fp32->bf16 inline, K=60 pad 64), B = Wencb,
// 2 N-tiles (u 0-15, 16-31) x 2 K-tiles = 4 MFMAs. b_enc folded into LSTM bias.
// Memory-bound: 251 MB read + 64 MB write.
// ---------------------------------------------------------------------------
__global__ __launch_bounds__(256) void encoder(const float* __restrict__ c,
                                               const __hip_bfloat16* __restrict__ Wencb,
                                               __hip_bfloat16* __restrict__ x) {
  const int lane = threadIdx.x & 63, wave = threadIdx.x >> 6;
  const int q = lane >> 4, l15 = lane & 15;
  const size_t r0 = ((size_t)blockIdx.x * 4 + wave) * 16;

  bfrag8 bf00 = *(const bfrag8*)(Wencb + (0 * 16 + l15) * 64 + 0 * 32 + q * 8);
  bfrag8 bf01 = *(const bfrag8*)(Wencb + (0 * 16 + l15) * 64 + 1 * 32 + q * 8);
  bfrag8 bf10 = *(const bfrag8*)(Wencb + (1 * 16 + l15) * 64 + 0 * 32 + q * 8);
  bfrag8 bf11 = *(const bfrag8*)(Wencb + (1 * 16 + l15) * 64 + 1 * 32 + q * 8);

  const float* cr = c + (r0 + l15) * 60;   // A row = l15
  float4 a0 = *(const float4*)(cr + q * 8);          // k = q*8 .. +3
  float4 a1 = *(const float4*)(cr + q * 8 + 4);      // k = q*8+4 .. +7
  float4 a2 = *(const float4*)(cr + 32 + q * 8);     // k = 32+q*8 (q=3: 56-59)
  float4 a3 = (q == 3) ? float4{0.f, 0.f, 0.f, 0.f}  // k 60-63 pad
                       : *(const float4*)(cr + 36 + q * 8);
  union { bfrag8 v; __hip_bfloat16 h[8]; } A0, A1;
  A0.h[0] = __float2bfloat16(a0.x); A0.h[1] = __float2bfloat16(a0.y);
  A0.h[2] = __float2bfloat16(a0.z); A0.h[3] = __float2bfloat16(a0.w);
  A0.h[4] = __float2bfloat16(a1.x); A0.h[5] = __float2bfloat16(a1.y);
  A0.h[6] = __float2bfloat16(a1.z); A0.h[7] = __float2bfloat16(a1.w);
  A1.h[0] = __float2bfloat16(a2.x); A1.h[1] = __float2bfloat16(a2.y);
  A1.h[2] = __float2bfloat16(a2.z); A1.h[3] = __float2bfloat16(a2.w);
  A1.h[4] = __float2bfloat16(a3.x); A1.h[5] = __float2bfloat16(a3.y);
  A1.h[6] = __float2bfloat16(a3.z); A1.h[7] = __float2bfloat16(a3.w);

  f32x4 acc0 = {0.f, 0.f, 0.f, 0.f}, acc1 = {0.f, 0.f, 0.f, 0.f};
  acc0 = __builtin_amdgcn_mfma_f32_16x16x32_bf16(A0.v, bf00, acc0, 0, 0, 0);
  acc1 = __builtin_amdgcn_mfma_f32_16x16x32_bf16(A0.v, bf10, acc1, 0, 0, 0);
  acc0 = __builtin_amdgcn_mfma_f32_16x16x32_bf16(A1.v, bf01, acc0, 0, 0, 0);
  acc1 = __builtin_amdgcn_mfma_f32_16x16x32_bf16(A1.v, bf11, acc1, 0, 0, 0);

#pragma unroll
  for (int r = 0; r < 4; ++r) {  // D: col = l15, row = q*4 + r
    size_t row = r0 + q * 4 + r;
    x[row * 32 + l15]      = __float2bfloat16(acc0[r]);
    x[row * 32 + 16 + l15] = __float2bfloat16(acc1[r]);
  }
}

// ---------------------------------------------------------------------------
// Kernel 2: fused LSTM weights, K=96, GATE-PERMUTED for the 4-tile layout.
// Permuted row np = wave*64 + tile*16 + c  (wave=np>>6, tile=(np>>4)&3, c=np&15):
//   unit = wave*16 + tile*4 + (c>>2), gate = c&3, orig row no = gate*64 + unit.
// Wc[dir][np][0:32) = W_ih, [32:96) = W_hh (bf16).
// biasc[dir][np] = b[no] + W_ih[no]·b_enc  (fp32).
// ---------------------------------------------------------------------------
__global__ void prep_weights(const float* __restrict__ b_enc,
                             const float* __restrict__ W_ih_f,
                             const float* __restrict__ W_hh_f,
                             const float* __restrict__ b_f,
                             const float* __restrict__ W_ih_b,
                             const float* __restrict__ W_hh_b,
                             const float* __restrict__ b_b,
                             __hip_bfloat16* __restrict__ Wc,
                             float* __restrict__ biasc) {
  const int dir = blockIdx.x;
  const int np = threadIdx.x;
  const int w = np >> 6, tile = (np >> 4) & 3, cc = np & 15;
  const int unit = w * 16 + tile * 4 + (cc >> 2);
  const int gate = cc & 3;
  const int no = gate * 64 + unit;
  const float* W_ih = dir ? W_ih_b : W_ih_f;
  const float* W_hh = dir ? W_hh_b : W_hh_f;
  const float* bv = dir ? b_b : b_f;
  __hip_bfloat16* row = Wc + (size_t)(dir * 256 + np) * 96;
#pragma unroll
  for (int k = 0; k < 32; ++k) row[k] = __float2bfloat16(W_ih[no * 32 + k]);
#pragma unroll
  for (int j = 0; j < 64; ++j) row[32 + j] = __float2bfloat16(W_hh[no * 64 + j]);
  float bb = bv[no];
#pragma unroll
  for (int e = 0; e < 32; ++e) bb += W_ih[no * 32 + e] * b_enc[e];
  biasc[dir * 256 + np] = bb;
}

// ---------------------------------------------------------------------------
// Kernel 3: the recurrence. 512 WGs = 256 batches x 2 dirs, 256 thr (4 waves).
// 2 WGs/CU: independent barriers interleave -> latency hidden, ~MFMA-pipe-bound.
// Per wave: 4 N-tiles (64 permuted gate cols), K=96:
//   K [0,32)  = x frag from REGISTERS (bf16, global prefetch depth 4; all A
//               rows identical: batch-1, rows broadcast)
//   K [32,96) = h from LDS ping-pong (2 x ds_read_b128, broadcast addresses)
// 12 MFMAs/wave (x-chain 1 deep, h-chain 2 deep). Epilogue: lane owns ONE gate
// value (tile=quad, col=l15) -> 1 fact/lane; aligned 4-lane group = 4 gates of
// one unit -> DPP gather; redundant cell update; 1 lgkm-only barrier per step.
// ---------------------------------------------------------------------------
__global__ __launch_bounds__(256, 2) void lstm_main(
    const __hip_bfloat16* __restrict__ x, const __hip_bfloat16* __restrict__ Wc,
    const float* __restrict__ biasc, float* __restrict__ cfin) {
  __shared__ short Hbuf[2][64];  // [buf][unit] bf16

  const int tid = threadIdx.x, lane = tid & 63, wave = tid >> 6;
  const int quad = lane >> 4, l15 = lane & 15;
  const int g = lane & 3;
  const int unit = wave * 16 + quad * 4 + (l15 >> 2);
  const int dir = (int)blockIdx.x & 1;
  const int b = (int)blockIdx.x >> 1;

  // loop-invariant weight fragments (B-operand: lane = col, k = quad*8+j)
  bfrag8 wf[4][3];
  float bias[4];
#pragma unroll
  for (int tl = 0; tl < 4; ++tl) {
    const int np = wave * 64 + tl * 16 + l15;
    const __hip_bfloat16* wr = Wc + (size_t)(dir * 256 + np) * 96 + quad * 8;
#pragma unroll
    for (int kt = 0; kt < 3; ++kt) wf[tl][kt] = *(const bfrag8*)(wr + kt * 32);
    bias[tl] = biasc[dir * 256 + np];
  }

  // activation constants for my gate column (g==2 is the tanh gate)
  const bool isg = (g == 2);
  const float S = isg ? 2.8853900817779268f : -1.4426950408889634f;
  const float Aa = isg ? 1.0f : 0.0f;
  const float Bb = isg ? -2.0f : 1.0f;

  const __hip_bfloat16* xr = x + (size_t)b * T_LEN * 32 + quad * 8;

  if (tid < 128) ((short*)Hbuf)[tid] = 0;  // h0 = 0 (both buffers)

  bfrag8 xb[4];
#pragma unroll
  for (int qq = 0; qq < 4; ++qq) {  // prefetch x frags for t = 0..3
    int tp = dir ? (T_LEN - 1 - qq) : qq;
    xb[qq] = *(const bfrag8*)(xr + (size_t)tp * 32);
  }

  float cst = 0.f;
  wg_barrier();

#pragma unroll 4
  for (int t = 0; t < T_LEN; ++t) {
    const int cur = t & 1;
    // h A-frags: addresses lane-uniform per quad -> pure broadcast, no conflict
    bfrag8 ahA = *(const bfrag8*)&Hbuf[cur][quad * 8];       // units q*8..q*8+7
    bfrag8 ahB = *(const bfrag8*)&Hbuf[cur][32 + quad * 8];  // units 32+q*8..
    // ---- MFMAs: x-chain (regs, 1 deep) + h-chain (after ds, 2 deep) ----
    f32x4 ax0 = {bias[0], bias[0], bias[0], bias[0]};
    f32x4 ax1 = {bias[1], bias[1], bias[1], bias[1]};
    f32x4 ax2 = {bias[2], bias[2], bias[2], bias[2]};
    f32x4 ax3 = {bias[3], bias[3], bias[3], bias[3]};
    ax0 = __builtin_amdgcn_mfma_f32_16x16x32_bf16(xb[t & 3], wf[0][0], ax0, 0, 0, 0);
    ax1 = __builtin_amdgcn_mfma_f32_16x16x32_bf16(xb[t & 3], wf[1][0], ax1, 0, 0, 0);
    ax2 = __builtin_amdgcn_mfma_f32_16x16x32_bf16(xb[t & 3], wf[2][0], ax2, 0, 0, 0);
    ax3 = __builtin_amdgcn_mfma_f32_16x16x32_bf16(xb[t & 3], wf[3][0], ax3, 0, 0, 0);
    f32x4 ah0 = {0.f, 0.f, 0.f, 0.f}, ah1 = {0.f, 0.f, 0.f, 0.f};
    f32x4 ah2 = {0.f, 0.f, 0.f, 0.f}, ah3 = {0.f, 0.f, 0.f, 0.f};
    ah0 = __builtin_amdgcn_mfma_f32_16x16x32_bf16(ahA, wf[0][1], ah0, 0, 0, 0);
    ah1 = __builtin_amdgcn_mfma_f32_16x16x32_bf16(ahA, wf[1][1], ah1, 0, 0, 0);
    ah2 = __builtin_amdgcn_mfma_f32_16x16x32_bf16(ahA, wf[2][1], ah2, 0, 0, 0);
    ah3 = __builtin_amdgcn_mfma_f32_16x16x32_bf16(ahA, wf[3][1], ah3, 0, 0, 0);
    ah0 = __builtin_amdgcn_mfma_f32_16x16x32_bf16(ahB, wf[0][2], ah0, 0, 0, 0);
    ah1 = __builtin_amdgcn_mfma_f32_16x16x32_bf16(ahB, wf[1][2], ah1, 0, 0, 0);
    ah2 = __builtin_amdgcn_mfma_f32_16x16x32_bf16(ahB, wf[2][2], ah2, 0, 0, 0);
    ah3 = __builtin_amdgcn_mfma_f32_16x16x32_bf16(ahB, wf[3][2], ah3, 0, 0, 0);
    {  // prefetch x frag for t+4 (stays in flight across the lgkm barrier)
      int tn = t + 4; if (tn > T_LEN - 1) tn = T_LEN - 1;
      int tp = dir ? (T_LEN - 1 - tn) : tn;
      xb[t & 3] = *(const bfrag8*)(xr + (size_t)tp * 32);
    }
    // ---- my gate value: tile = quad, any row reg (rows batch-dup) -> reg 0
    float vx01 = (quad & 1) ? ax1[0] : ax0[0];
    float vx23 = (quad & 1) ? ax3[0] : ax2[0];
    float vx = (quad & 2) ? vx23 : vx01;
    float vh01 = (quad & 1) ? ah1[0] : ah0[0];
    float vh23 = (quad & 1) ? ah3[0] : ah2[0];
    float vh = (quad & 2) ? vh23 : vh01;
    float a = fact(vx + vh, S, Aa, Bb);
    // gather the 4 gates of my unit from my aligned 4-lane group (i,f,g,o)
    float gi = qb<0>(a), gf = qb<1>(a), gg = qb<2>(a), go = qb<3>(a);
    cst = gf * cst + gi * gg;
    float h = go * ftanh(cst);
    if (g == 0) *(__hip_bfloat16*)&Hbuf[cur ^ 1][unit] = __float2bfloat16(h);
    wg_barrier();
  }

  if (g == 0) {  // reference quirk: final CELL state feeds the FC
    cfin[(size_t)(dir * 256 + b) * 64 + unit] = cst;
  }
}

// ---------------------------------------------------------------------------
// Kernel 4: out[b,:] = [c_fwd(b) ; c_bwd(b)] @ W_fin^T + b_fin
// ---------------------------------------------------------------------------
__global__ void final_fc(const float* __restrict__ cfin,
                         const float* __restrict__ W_fin,
                         const float* __restrict__ b_fin,
                         float* __restrict__ out) {
  int b = threadIdx.x;  // 256 threads, 1 block
  const float* cf = cfin + (size_t)b * 64;
  const float* cb = cfin + (size_t)(256 + b) * 64;
  float a0 = b_fin[0], a1 = b_fin[1], a2 = b_fin[2];
  for (int u = 0; u < 64; ++u) {
    float vf = cf[u], vb = cb[u];
    a0 += W_fin[0 * 128 + u] * vf + W_fin[0 * 128 + 64 + u] * vb;
    a1 += W_fin[1 * 128 + u] * vf + W_fin[1 * 128 + 64 + u] * vb;
    a2 += W_fin[2 * 128 + u] * vf + W_fin[2 * 128 + 64 + u] * vb;
  }
  out[b * 3 + 0] = a0;
  out[b * 3 + 1] = a1;
  out[b * 3 + 2] = a2;
}

extern "C" void kernel_launch(void* const* d_in, const int* in_sizes, int n_in,
                              void* d_out, int out_size, void* d_ws, size_t ws_size,
                              hipStream_t stream) {
  (void)in_sizes; (void)n_in; (void)out_size; (void)ws_size;
  const float* c      = (const float*)d_in[0];
  const float* W_enc  = (const float*)d_in[1];
  const float* b_enc  = (const float*)d_in[2];
  const float* W_ih_f = (const float*)d_in[3];
  const float* W_hh_f = (const float*)d_in[4];
  const float* b_f    = (const float*)d_in[5];
  const float* W_ih_b = (const float*)d_in[6];
  const float* W_hh_b = (const float*)d_in[7];
  const float* b_b    = (const float*)d_in[8];
  const float* W_fin  = (const float*)d_in[9];
  const float* b_fin  = (const float*)d_in[10];
  float* out = (float*)d_out;

  char* ws = (char*)d_ws;
  __hip_bfloat16* x     = (__hip_bfloat16*)ws;                      // 64 MiB
  __hip_bfloat16* Wc    = (__hip_bfloat16*)(ws + 67108864);         // 98304 B
  float* biasc          = (float*)(ws + 67108864 + 98304);          // 2048 B
  __hip_bfloat16* Wencb = (__hip_bfloat16*)(ws + 67108864 + 100352); // 4096 B
  float* cfin           = (float*)(ws + 67108864 + 104448);         // 131072 B

  prep_enc<<<1, 32, 0, stream>>>(W_enc, Wencb);
  prep_weights<<<2, 256, 0, stream>>>(b_enc, W_ih_f, W_hh_f, b_f,
                                      W_ih_b, W_hh_b, b_b, Wc, biasc);
  encoder<<<16384, 256, 0, stream>>>(c, Wencb, x);
  lstm_main<<<512, 256, 0, stream>>>(x, Wc, biasc, cfin);
  final_fc<<<1, 256, 0, stream>>>(cfin, W_fin, b_fin, out);
}